// Round 11
// baseline (345.149 us; speedup 1.0000x reference)
//
#include <hip/hip_runtime.h>
#include <hip/hip_bf16.h>
#include <stdint.h>
#include <type_traits>

// B=16384, IN=1024, H=1024, K = IN+H = 2048
// Gate order: 0=i, 1=f, 2=o, 3=u
// ws: A_bf16 [16384][2048] @ 0 (64 MiB); B_bf16 [4][1024][2048] (j-major = W^T) @ 64 MiB

typedef short bf16x8 __attribute__((ext_vector_type(8)));
typedef unsigned short u16x8 __attribute__((ext_vector_type(8)));
typedef float f32x4 __attribute__((ext_vector_type(4)));

__device__ __forceinline__ unsigned short f2bf(float f) {
    union { float f; uint32_t u; } v; v.f = f;
    uint32_t r = v.u + 0x7FFFu + ((v.u >> 16) & 1u);   // RNE
    return (unsigned short)(r >> 16);
}

__device__ __forceinline__ float fsig(float x) { return 1.0f / (1.0f + __expf(-x)); }
__device__ __forceinline__ float ftanh(float x) { return 2.0f * fsig(2.0f * x) - 1.0f; }

// ---------------- pack A: [input | prev_h] -> bf16 [16384][2048] ----------------
__global__ __launch_bounds__(256) void pack_a_kernel(const float* __restrict__ input,
                                                     const float* __restrict__ prev_h,
                                                     unsigned short* __restrict__ Apk) {
    long idx = (long)blockIdx.x * 256 + threadIdx.x;
    long e0 = idx * 8;
    int b = (int)(e0 >> 11);
    int k = (int)(e0 & 2047);
    const float* src = (k < 1024) ? (input + (size_t)b * 1024 + k)
                                  : (prev_h + (size_t)b * 1024 + (k - 1024));
    float4 lo = *(const float4*)src;
    float4 hi = *(const float4*)(src + 4);
    u16x8 o;
    o[0] = f2bf(lo.x); o[1] = f2bf(lo.y); o[2] = f2bf(lo.z); o[3] = f2bf(lo.w);
    o[4] = f2bf(hi.x); o[5] = f2bf(hi.y); o[6] = f2bf(hi.z); o[7] = f2bf(hi.w);
    *(u16x8*)(Apk + e0) = o;
}

// ---------------- pack B: per-gate W^T (j-major) bf16 [4][1024][2048] ----------------
__global__ __launch_bounds__(256) void pack_b_kernel(
        const float* __restrict__ wxi, const float* __restrict__ wxf,
        const float* __restrict__ wxo, const float* __restrict__ wxu,
        const float* __restrict__ whi, const float* __restrict__ whf,
        const float* __restrict__ who, const float* __restrict__ whu,
        unsigned short* __restrict__ Bpk) {
    int idx = blockIdx.x * 256 + threadIdx.x;
    int g  = idx >> 18;
    int r  = idx & 262143;
    int kc = r >> 10;
    int j  = r & 1023;
    const float* wx = (g == 0) ? wxi : (g == 1) ? wxf : (g == 2) ? wxo : wxu;
    const float* wh = (g == 0) ? whi : (g == 1) ? whf : (g == 2) ? who : whu;
    int k0 = kc * 8;
    const float* src = (k0 < 1024) ? (wx + (size_t)k0 * 1024 + j)
                                   : (wh + (size_t)(k0 - 1024) * 1024 + j);
    u16x8 o;
#pragma unroll
    for (int t = 0; t < 8; ++t) o[t] = f2bf(src[(size_t)t * 1024]);
    *(u16x8*)(Bpk + (((size_t)(g * 1024 + j)) << 11) + k0) = o;
}

// ---------------- fused GEMM + LSTM epilogue (single-barrier free-run slices) ----------------
// grid 1024 = 64 rowTiles x 16 colTiles; block 512 = 8 waves.
// wave w: wm = w>>2 (128-row half), wq = w&3 (16-col quarter per gate).
// Per wave: 128 rows x 16 cols x 4 gates -> acc[8][4] f32x4; epilogue lane-local.
// K-loop: BK=32 slices, 4 LDS buffers x 32 KiB, staging lookahead t+2.
// Slice t = ONE free-run segment: {STAGE(t+2); 12 ds_read; 32 MFMA (compiler
// dep-waits only); vmcnt(4); BAR}. One barrier per slice -> waves desynchronize
// within the slice, so laggards' ds_reads drain on the LDS pipe while leaders'
// MFMAs occupy the matrix pipe (T3-minimum recipe; no forced lgkm, no setprio,
// no sched hints).
// vmcnt(4) @ slice t: outstanding = GLL(t+1)x4 + GLL(t+2)x4 -> drains t+1's
// (needed after this barrier), leaves t+2's in flight.

#define GLL(gp, lp) __builtin_amdgcn_global_load_lds( \
        (__attribute__((address_space(1))) void*)(gp), \
        (__attribute__((address_space(3))) void*)(lp), 16, 0, 0)

#define BAR() do { asm volatile("" ::: "memory"); __builtin_amdgcn_s_barrier(); \
                   asm volatile("" ::: "memory"); } while (0)

__global__ __launch_bounds__(512, 2) void lstm_gemm_kernel(
        const unsigned short* __restrict__ Apk,   // [16384][2048]
        const unsigned short* __restrict__ Bpk,   // [4][1024][2048] j-major
        const float* __restrict__ prev_c,
        const float* __restrict__ bi, const float* __restrict__ bf_,
        const float* __restrict__ bo, const float* __restrict__ bu,
        float* __restrict__ out_h, float* __restrict__ out_c) {
    __shared__ __align__(16) unsigned char smem[131072];
    const int tid = threadIdx.x;
    const int w = tid >> 6, l = tid & 63;
    const int lr = l & 15, s4 = l >> 4;
    const int wm = w >> 2, wq = w & 3;

    // XCD-aware bijective swizzle (nwg=1024 % 8 == 0)
    const int bid = blockIdx.x;
    const int sw = ((bid & 7) << 7) + (bid >> 3);
    const int tileRow = sw & 63, tileCol = sw >> 6;
    const int rowBase = tileRow * 256;
    const int jBase = tileCol * 64;

    // read-side swizzled slot byte offset (involution with staging-side slot)
    const int swr = ((s4 ^ ((lr >> 1) & 3)) << 4);

    int aoff[8], boff[4];
#pragma unroll
    for (int m = 0; m < 8; ++m) aoff[m] = (wm * 128 + m * 16 + lr) * 64 + swr;
#pragma unroll
    for (int g = 0; g < 4; ++g) boff[g] = 16384 + (g * 64 + wq * 16 + lr) * 64 + swr;

    // staging: per-lane pre-swizzled global sources; wave-uniform LDS bases
    const int slot = (l & 3) ^ ((l >> 3) & 3);
    const int rloc = w * 16 + (l >> 2);           // 0..127
    const unsigned short* aSrc0 = Apk + (size_t)(rowBase + rloc) * 2048 + slot * 8;
    const unsigned short* aSrc1 = Apk + (size_t)(rowBase + 128 + rloc) * 2048 + slot * 8;
    const int br0 = rloc, br1 = 128 + rloc;
    const unsigned short* bSrc0 = Bpk + (((size_t)((br0 >> 6) * 1024 + jBase + (br0 & 63))) << 11) + slot * 8;
    const unsigned short* bSrc1 = Bpk + (((size_t)((br1 >> 6) * 1024 + jBase + (br1 & 63))) << 11) + slot * 8;
    const int aDst0 = w * 1024;
    const int aDst1 = 8192 + w * 1024;
    const int bDst0 = 16384 + w * 1024;
    const int bDst1 = 24576 + w * 1024;

#define STAGE4(T) do { const int _bb = ((T) & 3) * 32768; \
        GLL(aSrc0 + (size_t)(T) * 32, smem + _bb + aDst0); \
        GLL(aSrc1 + (size_t)(T) * 32, smem + _bb + aDst1); \
        GLL(bSrc0 + (size_t)(T) * 32, smem + _bb + bDst0); \
        GLL(bSrc1 + (size_t)(T) * 32, smem + _bb + bDst1); } while (0)

    f32x4 acc[8][4];
    const f32x4 vzero = {0.f, 0.f, 0.f, 0.f};
#pragma unroll
    for (int m = 0; m < 8; ++m)
#pragma unroll
        for (int g = 0; g < 4; ++g) acc[m][g] = vzero;

    // prologue: stage slices 0,1; drain slice-0 loads (leave slice-1 in flight)
    STAGE4(0); STAGE4(1);
    asm volatile("s_waitcnt vmcnt(4)" ::: "memory");
    BAR();

    auto slice = [&](int t, auto vnc, auto stgc) {
        constexpr int VN = decltype(vnc)::value;   // 4 steady; 0 = drain; -1 = none
        constexpr bool STG = decltype(stgc)::value;
        const int bt = (t & 3) * 32768;
        if constexpr (STG) STAGE4(t + 2);
        bf16x8 bv[4], av[8];
#pragma unroll
        for (int g = 0; g < 4; ++g) bv[g] = *(const bf16x8*)(smem + bt + boff[g]);
#pragma unroll
        for (int m = 0; m < 8; ++m) av[m] = *(const bf16x8*)(smem + bt + aoff[m]);
#pragma unroll
        for (int m = 0; m < 8; ++m)
#pragma unroll
            for (int g = 0; g < 4; ++g)
                acc[m][g] = __builtin_amdgcn_mfma_f32_16x16x32_bf16(av[m], bv[g], acc[m][g], 0, 0, 0);
        if constexpr (VN == 4)      asm volatile("s_waitcnt vmcnt(4)" ::: "memory");
        else if constexpr (VN == 0) asm volatile("s_waitcnt vmcnt(0)" ::: "memory");
        if constexpr (VN >= 0) BAR();
    };

    using c4 = std::integral_constant<int, 4>;
    using c0 = std::integral_constant<int, 0>;
    using cm = std::integral_constant<int, -1>;
    using bT = std::integral_constant<bool, true>;
    using bF = std::integral_constant<bool, false>;

#pragma unroll 1
    for (int t = 0; t < 62; ++t) slice(t, c4{}, bT{});   // t=61 stages slice 63
    slice(62, c0{}, bF{});
    slice(63, cm{}, bF{});

    // ---- epilogue: fully lane-local (all 4 gates in-register) ----
    const int colIdx = jBase + wq * 16 + lr;
    const float vbi = bi[colIdx], vbf = bf_[colIdx], vbo = bo[colIdx], vbu = bu[colIdx];
    const int rowB = rowBase + wm * 128 + s4 * 4;
#pragma unroll
    for (int m = 0; m < 8; ++m) {
#pragma unroll
        for (int tt = 0; tt < 4; ++tt) {
            const size_t idx = (size_t)(rowB + m * 16 + tt) * 1024 + colIdx;
            float zi = acc[m][0][tt] + vbi;
            float zf = acc[m][1][tt] + vbf;
            float zo = acc[m][2][tt] + vbo;
            float zu = acc[m][3][tt] + vbu;
            float iv = fsig(zi), fv = fsig(zf), ov = fsig(zo), uv = ftanh(zu);
            float cv = fv * prev_c[idx] + iv * uv;
            out_c[idx] = cv;
            out_h[idx] = ov * ftanh(cv);
        }
    }
#undef STAGE4
}

extern "C" void kernel_launch(void* const* d_in, const int* in_sizes, int n_in,
                              void* d_out, int out_size, void* d_ws, size_t ws_size,
                              hipStream_t stream) {
    const float* input  = (const float*)d_in[0];
    const float* prev_h = (const float*)d_in[1];
    const float* prev_c = (const float*)d_in[2];
    const float* wxi = (const float*)d_in[3];
    const float* whi = (const float*)d_in[4];
    const float* wxf = (const float*)d_in[5];
    const float* whf = (const float*)d_in[6];
    const float* wxu = (const float*)d_in[7];
    const float* whu = (const float*)d_in[8];
    const float* wxo = (const float*)d_in[9];
    const float* who = (const float*)d_in[10];
    const float* bi  = (const float*)d_in[11];
    const float* bf_ = (const float*)d_in[12];
    const float* bo  = (const float*)d_in[13];
    const float* bu  = (const float*)d_in[14];

    unsigned short* Apk = (unsigned short*)d_ws;                                  // 64 MiB
    unsigned short* Bpk = (unsigned short*)((char*)d_ws + (size_t)67108864);      // 16 MiB

    float* out_h = (float*)d_out;
    float* out_c = out_h + (size_t)16384 * 1024;

    pack_a_kernel<<<dim3(16384), dim3(256), 0, stream>>>(input, prev_h, Apk);
    pack_b_kernel<<<dim3(4096), dim3(256), 0, stream>>>(wxi, wxf, wxo, wxu,
                                                        whi, whf, who, whu, Bpk);
    lstm_gemm_kernel<<<dim3(1024), dim3(512), 0, stream>>>(Apk, Bpk, prev_c,
                                                           bi, bf_, bo, bu, out_h, out_c);
}